// Round 7
// baseline (465.922 us; speedup 1.0000x reference)
//
#include <hip/hip_runtime.h>
#include <cstdint>
#include <cstddef>

// ---------------------------------------------------------------------------
// R7 = MEASUREMENT ROUND.  Exact R2 pipeline, but expand1 is launched with
// grid.z = 8 and expand3 with grid.z = 4 (kernels ignore blockIdx.z, so the
// z-copies do identical work writing identical values -- deterministic and
// validation-safe).  This pushes both dispatches past the ~117 us harness
// fills so they finally appear in the rocprof top-5 with full counters.
// Per-copy time = dispatch_dur / z.  Next round reverts z to 1.
// ---------------------------------------------------------------------------

typedef _Float16 f16;
typedef __attribute__((ext_vector_type(8))) _Float16 f16x8;
typedef __attribute__((ext_vector_type(4))) _Float16 f16x4;
typedef __attribute__((ext_vector_type(4))) float    f32x4;

#define MFMA(a, b, c) __builtin_amdgcn_mfma_f32_16x16x32_f16((a), (b), (c), 0, 0, 0)

#define NIMG 32
#define CIN  512
#define HW   3136     // 56*56
#define W56  56
#define CSQ  64
#define CE   256

// ---------------------------------------------------------------------------
// prep: fp32 -> fp16 weight conversion + W3 repack to [tap][o][i]
// ---------------------------------------------------------------------------
__global__ __launch_bounds__(256) void fire_prep(
    const float* __restrict__ sw, const float* __restrict__ e1w,
    const float* __restrict__ e3w,
    f16* __restrict__ Wsq, f16* __restrict__ W1, f16* __restrict__ W3)
{
    int t = blockIdx.x * 256 + threadIdx.x;
    if (t < CSQ * CIN) {
        Wsq[t] = (f16)sw[t];
    } else if (t < CSQ * CIN + CE * CSQ) {
        int j = t - CSQ * CIN;
        W1[j] = (f16)e1w[j];
    } else {
        int j = t - (CSQ * CIN + CE * CSQ);
        if (j < 9 * CE * CSQ) {
            int tap = j >> 14;            // 16384 = 256*64 per tap
            int rem = j & 16383;
            int o = rem >> 6;
            int i = rem & 63;
            W3[j] = (f16)e3w[(o * CSQ + i) * 9 + tap];
        }
    }
}

// ---------------------------------------------------------------------------
// squeeze v2: S[n][p][64] = relu(Wsq[64x512] @ x[n][512][p] + b)  (fp16 out)
// ---------------------------------------------------------------------------
__global__ __launch_bounds__(256) void fire_squeeze2(
    const float* __restrict__ x, const float* __restrict__ sb,
    const f16* __restrict__ Wsq, f16* __restrict__ Sws)
{
    const int tid  = threadIdx.x;
    const int lane = tid & 63, wv = tid >> 6;
    const int i = lane & 15, g = lane >> 4;
    const int w  = blockIdx.x * 4 + wv;     // 0..1567
    const int n  = w / 49;
    const int p0 = (w % 49) * 64;

    const float* xp = x + (size_t)n * CIN * HW + p0 + 4 * i;

    f32x4 acc[4][4] = {};
    #pragma unroll
    for (int kk = 0; kk < 16; ++kk) {
        const int k0 = kk * 32 + g * 8;
        f16x8 b[4];
        #pragma unroll
        for (int v = 0; v < 8; ++v) {
            float4 q = *(const float4*)(xp + (size_t)(k0 + v) * HW);
            b[0][v] = (f16)q.x;
            b[1][v] = (f16)q.y;
            b[2][v] = (f16)q.z;
            b[3][v] = (f16)q.w;
        }
        #pragma unroll
        for (int m = 0; m < 4; ++m) {
            f16x8 a = *(const f16x8*)(Wsq + (16 * m + i) * CIN + k0);
            #pragma unroll
            for (int c = 0; c < 4; ++c)
                acc[m][c] = MFMA(a, b[c], acc[m][c]);
        }
    }

    #pragma unroll
    for (int m = 0; m < 4; ++m) {
        const int oc = 16 * m + 4 * g;
        const float4 bb = *(const float4*)(sb + oc);
        #pragma unroll
        for (int c = 0; c < 4; ++c) {
            const int px = p0 + 4 * i + c;
            f16x4 st;
            st[0] = (f16)fmaxf(acc[m][c][0] + bb.x, 0.f);
            st[1] = (f16)fmaxf(acc[m][c][1] + bb.y, 0.f);
            st[2] = (f16)fmaxf(acc[m][c][2] + bb.z, 0.f);
            st[3] = (f16)fmaxf(acc[m][c][3] + bb.w, 0.f);
            *(f16x4*)(Sws + ((size_t)n * HW + px) * CSQ + oc) = st;
        }
    }
}

// ---------------------------------------------------------------------------
// expand1x1 (R2 version): out[n][0:256][p] = relu(W1[256x64] @ S + b1)
// ---------------------------------------------------------------------------
__global__ __launch_bounds__(256) void fire_expand1(
    const f16* __restrict__ Sws, const f16* __restrict__ W1,
    const float* __restrict__ b1, float* __restrict__ out)
{
    const int tid  = threadIdx.x;
    const int lane = tid & 63, wv = tid >> 6;
    const int i = lane & 15, g = lane >> 4;
    const int n  = blockIdx.y;
    const int p0 = blockIdx.x * 64;

    f32x4 acc[4][4] = {};
    #pragma unroll
    for (int kk = 0; kk < 2; ++kk) {
        const int k0 = kk * 32 + g * 8;
        f16x8 b[4];
        #pragma unroll
        for (int c = 0; c < 4; ++c)
            b[c] = *(const f16x8*)(Sws + ((size_t)n * HW + p0 + 16 * c + i) * CSQ + k0);
        #pragma unroll
        for (int m = 0; m < 4; ++m) {
            f16x8 a = *(const f16x8*)(W1 + (64 * wv + 16 * m + i) * CSQ + k0);
            #pragma unroll
            for (int c = 0; c < 4; ++c)
                acc[m][c] = MFMA(a, b[c], acc[m][c]);
        }
    }

    #pragma unroll
    for (int m = 0; m < 4; ++m) {
        const int oc = 64 * wv + 16 * m + 4 * g;
        const float4 bb = *(const float4*)(b1 + oc);
        #pragma unroll
        for (int c = 0; c < 4; ++c) {
            float* op = out + ((size_t)n * 512 + oc) * HW + p0 + 16 * c + i;
            op[0 * (size_t)HW] = fmaxf(acc[m][c][0] + bb.x, 0.f);
            op[1 * (size_t)HW] = fmaxf(acc[m][c][1] + bb.y, 0.f);
            op[2 * (size_t)HW] = fmaxf(acc[m][c][2] + bb.z, 0.f);
            op[3 * (size_t)HW] = fmaxf(acc[m][c][3] + bb.w, 0.f);
        }
    }
}

// ---------------------------------------------------------------------------
// expand3x3 (R2 version): implicit GEMM, 9 taps, swizzled S tile in LDS
// ---------------------------------------------------------------------------
__global__ __launch_bounds__(256) void fire_expand3(
    const f16* __restrict__ Sws, const f16* __restrict__ W3,
    const float* __restrict__ b3, float* __restrict__ out)
{
    __shared__ f16 Slds[4 * 58 * 64];   // 29696 B

    const int tid  = threadIdx.x;
    const int lane = tid & 63, wv = tid >> 6;
    const int i = lane & 15, g = lane >> 4;
    const int n  = blockIdx.y;
    const int rb = blockIdx.x;          // 0..27 -> output rows 2rb, 2rb+1
    const int r0 = rb * 2;

    #pragma unroll
    for (int it = 0; it < 8; ++it) {
        int task = it * 256 + tid;
        if (task < 232 * 8) {
            int s  = task >> 3, ck = task & 7;
            int tr = s / 58,   tc = s % 58;
            int h = r0 - 1 + tr, w = tc - 1;
            int4 val = make_int4(0, 0, 0, 0);
            if (h >= 0 && h < W56 && w >= 0 && w < W56)
                val = *(const int4*)(Sws + ((size_t)n * HW + h * W56 + w) * CSQ + ck * 8);
            int off = s * 128 + ck * 16;
            off ^= ((s & 7) << 4);
            *(int4*)((char*)Slds + off) = val;
        }
    }
    __syncthreads();

    int q0[7];
    #pragma unroll
    for (int c = 0; c < 7; ++c) {
        int pl  = 16 * c + i;                 // 0..111
        int r   = (pl >= W56) ? 1 : 0;
        int col = pl - r * W56;
        q0[c] = r * 58 + col;
    }

    f32x4 acc[4][7] = {};
    for (int dh = 0; dh < 3; ++dh) {
        for (int dw = 0; dw < 3; ++dw) {
            const f16* wtap = W3 + (size_t)(dh * 3 + dw) * CE * CSQ;
            const int toff = dh * 58 + dw;
            #pragma unroll
            for (int kk = 0; kk < 2; ++kk) {
                const int k0 = kk * 32 + g * 8;
                f16x8 b[7];
                #pragma unroll
                for (int c = 0; c < 7; ++c) {
                    int q   = q0[c] + toff;
                    int off = (q * 128 + kk * 64 + g * 16) ^ ((q & 7) << 4);
                    b[c] = *(const f16x8*)((const char*)Slds + off);
                }
                #pragma unroll
                for (int m = 0; m < 4; ++m) {
                    f16x8 a = *(const f16x8*)(wtap + (64 * wv + 16 * m + i) * CSQ + k0);
                    #pragma unroll
                    for (int c = 0; c < 7; ++c)
                        acc[m][c] = MFMA(a, b[c], acc[m][c]);
                }
            }
        }
    }

    #pragma unroll
    for (int m = 0; m < 4; ++m) {
        const int ocl = 64 * wv + 16 * m + 4 * g;   // 0..255 within e3
        const float4 bb = *(const float4*)(b3 + ocl);
        #pragma unroll
        for (int c = 0; c < 7; ++c) {
            float* op = out + ((size_t)n * 512 + 256 + ocl) * HW + rb * 112 + 16 * c + i;
            op[0 * (size_t)HW] = fmaxf(acc[m][c][0] + bb.x, 0.f);
            op[1 * (size_t)HW] = fmaxf(acc[m][c][1] + bb.y, 0.f);
            op[2 * (size_t)HW] = fmaxf(acc[m][c][2] + bb.z, 0.f);
            op[3 * (size_t)HW] = fmaxf(acc[m][c][3] + bb.w, 0.f);
        }
    }
}

// ---------------------------------------------------------------------------
extern "C" void kernel_launch(void* const* d_in, const int* in_sizes, int n_in,
                              void* d_out, int out_size, void* d_ws, size_t ws_size,
                              hipStream_t stream)
{
    const float* x  = (const float*)d_in[0];
    const float* sw = (const float*)d_in[1];
    const float* sb = (const float*)d_in[2];
    const float* w1 = (const float*)d_in[3];
    const float* b1 = (const float*)d_in[4];
    const float* w3 = (const float*)d_in[5];
    const float* b3 = (const float*)d_in[6];
    float* out = (float*)d_out;

    // workspace layout (fp16): S [32][3136][64], Wsq [64][512],
    // W1 [256][64], W3 [9][256][64]
    f16* Sws = (f16*)d_ws;
    f16* Wsq = Sws + (size_t)NIMG * HW * CSQ;
    f16* W1b = Wsq + CSQ * CIN;
    f16* W3b = W1b + CE * CSQ;

    fire_prep<<<768, 256, 0, stream>>>(sw, w1, w3, Wsq, W1b, W3b);
    fire_squeeze2<<<392, 256, 0, stream>>>(x, sb, Wsq, Sws);
    // MEASUREMENT: z-replicated launches (identical work per z; kernels
    // ignore blockIdx.z).  Per-copy time = dispatch_dur / z.
    fire_expand1<<<dim3(49, 32, 8), 256, 0, stream>>>(Sws, W1b, b1, out);
    fire_expand3<<<dim3(28, 32, 4), 256, 0, stream>>>(Sws, W3b, b3, out);
}

// Round 8
// 294.397 us; speedup vs baseline: 1.5826x; 1.5826x over previous
//
#include <hip/hip_runtime.h>
#include <cstdint>
#include <cstddef>

// ---------------------------------------------------------------------------
// SqueezeNet fire module (R8):
//   prep:     weights -> fp16; W3 repacked [tap][kk][oc][h][8] for 32x32x16
//   squeeze2: x (coalesced float4) -> S fp16 [n][px][64]        (~38 us)
//   expand1:  R2 version (16x16x32)                              (~15-25 us)
//   expand3v3: REWRITTEN on mfma_f32_32x32x16_f16.
//     R7 counters showed e3 = 68.5 us, LDS-pipe + L2-weight-stream bound.
//     New: wave = 128 oc x 64 px (B-reuse 4, A-reuse 2), block = 4 waves
//     over a 4-row x 32-col tile; K-major LDS [kk][h][pos][16B] gives
//     conflict-free B-reads; A (weights) 1KB coalesced L1/L2 reads; stores
//     are 128-B contiguous runs.  LDS 9.8 B/output (was 18), L2-A halved.
// ---------------------------------------------------------------------------

typedef _Float16 f16;
typedef __attribute__((ext_vector_type(8)))  _Float16 f16x8;
typedef __attribute__((ext_vector_type(4)))  _Float16 f16x4;
typedef __attribute__((ext_vector_type(4)))  float    f32x4;
typedef __attribute__((ext_vector_type(16))) float    f32x16;

#define MFMA(a, b, c)   __builtin_amdgcn_mfma_f32_16x16x32_f16((a), (b), (c), 0, 0, 0)
#define MFMA32(a, b, c) __builtin_amdgcn_mfma_f32_32x32x16_f16((a), (b), (c), 0, 0, 0)

#define NIMG 32
#define CIN  512
#define HW   3136     // 56*56
#define W56  56
#define CSQ  64
#define CE   256

// ---------------------------------------------------------------------------
// prep: fp32 -> fp16 weights.  W3 -> [tap 9][kk 4][oc 256][h 2][v 8]
// (element (tap,kk,oc,h,v) = e3w[oc][k=kk*16+h*8+v] at spatial tap)
// ---------------------------------------------------------------------------
__global__ __launch_bounds__(256) void fire_prep(
    const float* __restrict__ sw, const float* __restrict__ e1w,
    const float* __restrict__ e3w,
    f16* __restrict__ Wsq, f16* __restrict__ W1, f16* __restrict__ W3)
{
    int t = blockIdx.x * 256 + threadIdx.x;
    if (t < CSQ * CIN) {
        Wsq[t] = (f16)sw[t];
    } else if (t < CSQ * CIN + CE * CSQ) {
        int j = t - CSQ * CIN;
        W1[j] = (f16)e1w[j];
    } else {
        int j = t - (CSQ * CIN + CE * CSQ);
        if (j < 9 * 4 * 256 * 16) {
            int v   = j & 7;
            int h   = (j >> 3) & 1;
            int o   = (j >> 4) & 255;
            int kk  = (j >> 12) & 3;
            int tap = j >> 14;                 // 0..8
            int ich = kk * 16 + h * 8 + v;     // 0..63
            W3[j] = (f16)e3w[(o * CSQ + ich) * 9 + tap];
        }
    }
}

// ---------------------------------------------------------------------------
// squeeze v2 (unchanged): S[n][p][64] = relu(Wsq @ x + b), fp16 out.
// ---------------------------------------------------------------------------
__global__ __launch_bounds__(256) void fire_squeeze2(
    const float* __restrict__ x, const float* __restrict__ sb,
    const f16* __restrict__ Wsq, f16* __restrict__ Sws)
{
    const int tid  = threadIdx.x;
    const int lane = tid & 63, wv = tid >> 6;
    const int i = lane & 15, g = lane >> 4;
    const int w  = blockIdx.x * 4 + wv;     // 0..1567
    const int n  = w / 49;
    const int p0 = (w % 49) * 64;

    const float* xp = x + (size_t)n * CIN * HW + p0 + 4 * i;

    f32x4 acc[4][4] = {};
    #pragma unroll
    for (int kk = 0; kk < 16; ++kk) {
        const int k0 = kk * 32 + g * 8;
        f16x8 b[4];
        #pragma unroll
        for (int v = 0; v < 8; ++v) {
            float4 q = *(const float4*)(xp + (size_t)(k0 + v) * HW);
            b[0][v] = (f16)q.x;
            b[1][v] = (f16)q.y;
            b[2][v] = (f16)q.z;
            b[3][v] = (f16)q.w;
        }
        #pragma unroll
        for (int m = 0; m < 4; ++m) {
            f16x8 a = *(const f16x8*)(Wsq + (16 * m + i) * CIN + k0);
            #pragma unroll
            for (int c = 0; c < 4; ++c)
                acc[m][c] = MFMA(a, b[c], acc[m][c]);
        }
    }

    #pragma unroll
    for (int m = 0; m < 4; ++m) {
        const int oc = 16 * m + 4 * g;
        const float4 bb = *(const float4*)(sb + oc);
        #pragma unroll
        for (int c = 0; c < 4; ++c) {
            const int px = p0 + 4 * i + c;
            f16x4 st;
            st[0] = (f16)fmaxf(acc[m][c][0] + bb.x, 0.f);
            st[1] = (f16)fmaxf(acc[m][c][1] + bb.y, 0.f);
            st[2] = (f16)fmaxf(acc[m][c][2] + bb.z, 0.f);
            st[3] = (f16)fmaxf(acc[m][c][3] + bb.w, 0.f);
            *(f16x4*)(Sws + ((size_t)n * HW + px) * CSQ + oc) = st;
        }
    }
}

// ---------------------------------------------------------------------------
// expand1x1 (R2 version, unchanged)
// ---------------------------------------------------------------------------
__global__ __launch_bounds__(256) void fire_expand1(
    const f16* __restrict__ Sws, const f16* __restrict__ W1,
    const float* __restrict__ b1, float* __restrict__ out)
{
    const int tid  = threadIdx.x;
    const int lane = tid & 63, wv = tid >> 6;
    const int i = lane & 15, g = lane >> 4;
    const int n  = blockIdx.y;
    const int p0 = blockIdx.x * 64;

    f32x4 acc[4][4] = {};
    #pragma unroll
    for (int kk = 0; kk < 2; ++kk) {
        const int k0 = kk * 32 + g * 8;
        f16x8 b[4];
        #pragma unroll
        for (int c = 0; c < 4; ++c)
            b[c] = *(const f16x8*)(Sws + ((size_t)n * HW + p0 + 16 * c + i) * CSQ + k0);
        #pragma unroll
        for (int m = 0; m < 4; ++m) {
            f16x8 a = *(const f16x8*)(W1 + (64 * wv + 16 * m + i) * CSQ + k0);
            #pragma unroll
            for (int c = 0; c < 4; ++c)
                acc[m][c] = MFMA(a, b[c], acc[m][c]);
        }
    }

    #pragma unroll
    for (int m = 0; m < 4; ++m) {
        const int oc = 64 * wv + 16 * m + 4 * g;
        const float4 bb = *(const float4*)(b1 + oc);
        #pragma unroll
        for (int c = 0; c < 4; ++c) {
            float* op = out + ((size_t)n * 512 + oc) * HW + p0 + 16 * c + i;
            op[0 * (size_t)HW] = fmaxf(acc[m][c][0] + bb.x, 0.f);
            op[1 * (size_t)HW] = fmaxf(acc[m][c][1] + bb.y, 0.f);
            op[2 * (size_t)HW] = fmaxf(acc[m][c][2] + bb.z, 0.f);
            op[3 * (size_t)HW] = fmaxf(acc[m][c][3] + bb.w, 0.f);
        }
    }
}

// ---------------------------------------------------------------------------
// expand3x3 v3 (32x32x16).  grid.x = 28 = 14 row-blocks x 2 col-blocks.
// Block tile: 4 rows x 32 cols x 256 oc.  4 waves = 2 oc-groups x 2 px-grps.
// LDS: K-major S halo [ck=kk*2+h (8)][pos (204 = 6r x 34c)][16 B].
// ---------------------------------------------------------------------------
__global__ __launch_bounds__(256) void fire_expand3v3(
    const f16* __restrict__ Sws, const f16* __restrict__ W3,
    const float* __restrict__ b3, float* __restrict__ out)
{
    __shared__ f16 SK[8 * 204 * 8];   // 26112 B

    const int tid  = threadIdx.x;
    const int lane = tid & 63, wv = tid >> 6;
    const int l31 = lane & 31, h = lane >> 5;
    const int wo = wv >> 1, wp = wv & 1;     // oc-group, px-group
    const int rb = blockIdx.x >> 1, cb = blockIdx.x & 1;
    const int n  = blockIdx.y;
    const int r0 = rb * 4;

    // ---- stage halo (6 rows x 34 cols) K-major, conflict-free writes ----
    if (tid < 204) {
        const int tr = tid / 34, tc = tid - tr * 34;
        const int hi = r0 - 1 + tr;
        const int wi = cb * 32 - 1 + tc;
        const bool inb = (hi >= 0 && hi < W56 && wi >= 0 && wi < W56);
        const f16* src = Sws + ((size_t)n * HW + hi * W56 + wi) * CSQ;
        #pragma unroll
        for (int ck = 0; ck < 8; ++ck) {
            int4 val = make_int4(0, 0, 0, 0);
            if (inb) val = *(const int4*)(src + ck * 8);
            *(int4*)((char*)SK + (ck * 204 + tid) * 16) = val;
        }
    }
    __syncthreads();

    f32x16 acc[4][2] = {};

    for (int tap = 0; tap < 9; ++tap) {
        const int dh = tap / 3, dw = tap - dh * 3;
        const int posb = (2 * wp + dh) * 34 + l31 + dw;
        const f16* wbase = W3 + (size_t)tap * 4 * 256 * 16;
        #pragma unroll
        for (int kk = 0; kk < 4; ++kk) {
            const char* kb = (const char*)SK + (kk * 2 + h) * 204 * 16;
            f16x8 B0 = *(const f16x8*)(kb + posb * 16);
            f16x8 B1 = *(const f16x8*)(kb + (posb + 34) * 16);
            #pragma unroll
            for (int om = 0; om < 4; ++om) {
                f16x8 A = *(const f16x8*)(wbase + (size_t)kk * 256 * 16
                                          + (wo * 128 + om * 32 + l31) * 16 + h * 8);
                acc[om][0] = MFMA32(A, B0, acc[om][0]);
                acc[om][1] = MFMA32(A, B1, acc[om][1]);
            }
        }
    }

    // ---- epilogue: D col = px = l31, row = ocl = (reg&3)+8*(reg>>2)+4*h ----
    const int colg = cb * 32 + l31;
    const bool ok = (colg < W56);
    #pragma unroll
    for (int om = 0; om < 4; ++om) {
        const int ocb = wo * 128 + om * 32;     // within e3's 256
        #pragma unroll
        for (int c = 0; c < 2; ++c) {
            const int row = r0 + 2 * wp + c;
            float* obase = out + ((size_t)n * 512 + 256 + ocb) * HW + row * W56 + colg;
            #pragma unroll
            for (int q = 0; q < 4; ++q) {
                const float4 bb = *(const float4*)(b3 + ocb + 8 * q + 4 * h);
                const float bbv[4] = {bb.x, bb.y, bb.z, bb.w};
                #pragma unroll
                for (int rv = 0; rv < 4; ++rv) {
                    const int ocl = 8 * q + 4 * h + rv;
                    const float val = fmaxf(acc[om][c][q * 4 + rv] + bbv[rv], 0.f);
                    if (ok) obase[(size_t)ocl * HW] = val;
                }
            }
        }
    }
}

// ---------------------------------------------------------------------------
extern "C" void kernel_launch(void* const* d_in, const int* in_sizes, int n_in,
                              void* d_out, int out_size, void* d_ws, size_t ws_size,
                              hipStream_t stream)
{
    const float* x  = (const float*)d_in[0];
    const float* sw = (const float*)d_in[1];
    const float* sb = (const float*)d_in[2];
    const float* w1 = (const float*)d_in[3];
    const float* b1 = (const float*)d_in[4];
    const float* w3 = (const float*)d_in[5];
    const float* b3 = (const float*)d_in[6];
    float* out = (float*)d_out;

    // workspace (fp16): S [32][3136][64], Wsq [64][512], W1 [256][64],
    // W3 [9][4][256][2][8]
    f16* Sws = (f16*)d_ws;
    f16* Wsq = Sws + (size_t)NIMG * HW * CSQ;
    f16* W1b = Wsq + CSQ * CIN;
    f16* W3b = W1b + CE * CSQ;

    fire_prep<<<768, 256, 0, stream>>>(sw, w1, w3, Wsq, W1b, W3b);
    fire_squeeze2<<<392, 256, 0, stream>>>(x, sb, Wsq, Sws);
    fire_expand1<<<dim3(49, 32), 256, 0, stream>>>(Sws, W1b, b1, out);
    fire_expand3v3<<<dim3(28, 32), 256, 0, stream>>>(Sws, W3b, b3, out);
}

// Round 9
// 213.802 us; speedup vs baseline: 2.1792x; 1.3770x over previous
//
#include <hip/hip_runtime.h>
#include <cstdint>
#include <cstddef>

// ---------------------------------------------------------------------------
// SqueezeNet fire module (R9):
//   prep:      weights -> fp16 (W3 [tap][o][i]) + zero whole padded-S buffer
//   squeeze2p: x (coalesced float4) -> Spad fp16 [n][58*58][64] (interior)
//   expand1p:  16x16x32, B-frags read directly from padded S (global, L2-hot)
//   expand3v4: v2 math/layout verbatim, but NO LDS staging / NO barriers:
//     B-frags read directly from zero-padded S (no predication), A from
//     L2-hot weights.  Waves fully independent -> max scheduling freedom;
//     R8 showed latency exposure (not LDS conflicts / not BW) is the sink.
// ---------------------------------------------------------------------------

typedef _Float16 f16;
typedef __attribute__((ext_vector_type(8))) _Float16 f16x8;
typedef __attribute__((ext_vector_type(4))) _Float16 f16x4;
typedef __attribute__((ext_vector_type(4))) float    f32x4;

#define MFMA(a, b, c) __builtin_amdgcn_mfma_f32_16x16x32_f16((a), (b), (c), 0, 0, 0)

#define NIMG 32
#define CIN  512
#define HW   3136     // 56*56
#define W56  56
#define PW   58       // padded width
#define SPAD 3364     // 58*58
#define CSQ  64
#define CE   256

// ---------------------------------------------------------------------------
// prep: weights -> fp16 (W3 repacked [tap][o][i]) ; tail blocks zero Spad.
// grid = 4132 * 256 threads = 196608 (weights) + 861184 (Spad int4 count)
// ---------------------------------------------------------------------------
__global__ __launch_bounds__(256) void fire_prep(
    const float* __restrict__ sw, const float* __restrict__ e1w,
    const float* __restrict__ e3w,
    f16* __restrict__ Wsq, f16* __restrict__ W1, f16* __restrict__ W3,
    f16* __restrict__ Spad)
{
    const int NW = CSQ * CIN + CE * CSQ + 9 * CE * CSQ;   // 196608
    int t = blockIdx.x * 256 + threadIdx.x;
    if (t < CSQ * CIN) {
        Wsq[t] = (f16)sw[t];
    } else if (t < CSQ * CIN + CE * CSQ) {
        int j = t - CSQ * CIN;
        W1[j] = (f16)e1w[j];
    } else if (t < NW) {
        int j = t - (CSQ * CIN + CE * CSQ);
        int tap = j >> 14;            // 16384 = 256*64 per tap
        int rem = j & 16383;
        int o = rem >> 6;
        int i = rem & 63;
        W3[j] = (f16)e3w[(o * CSQ + i) * 9 + tap];
    } else {
        int j = t - NW;               // 0 .. 861183
        if (j < NIMG * SPAD * CSQ / 8)
            ((int4*)Spad)[j] = make_int4(0, 0, 0, 0);
    }
}

// ---------------------------------------------------------------------------
// squeeze: Spad[n][(h+1)*58+w+1][64] = relu(Wsq @ x + b), fp16.
// wave-tile 64 px x 64 oc; coalesced float4 x loads (interleaved-px frags).
// ---------------------------------------------------------------------------
__global__ __launch_bounds__(256) void fire_squeeze2p(
    const float* __restrict__ x, const float* __restrict__ sb,
    const f16* __restrict__ Wsq, f16* __restrict__ Spad)
{
    const int tid  = threadIdx.x;
    const int lane = tid & 63, wv = tid >> 6;
    const int i = lane & 15, g = lane >> 4;
    const int w  = blockIdx.x * 4 + wv;     // 0..1567
    const int n  = w / 49;
    const int p0 = (w % 49) * 64;

    const float* xp = x + (size_t)n * CIN * HW + p0 + 4 * i;

    f32x4 acc[4][4] = {};
    #pragma unroll
    for (int kk = 0; kk < 16; ++kk) {
        const int k0 = kk * 32 + g * 8;
        f16x8 b[4];
        #pragma unroll
        for (int v = 0; v < 8; ++v) {
            float4 q = *(const float4*)(xp + (size_t)(k0 + v) * HW);
            b[0][v] = (f16)q.x;
            b[1][v] = (f16)q.y;
            b[2][v] = (f16)q.z;
            b[3][v] = (f16)q.w;
        }
        #pragma unroll
        for (int m = 0; m < 4; ++m) {
            f16x8 a = *(const f16x8*)(Wsq + (16 * m + i) * CIN + k0);
            #pragma unroll
            for (int c = 0; c < 4; ++c)
                acc[m][c] = MFMA(a, b[c], acc[m][c]);
        }
    }

    // store: D row = oc = 16m+4g+v, col = i -> pixel p0+4i+c (padded layout)
    #pragma unroll
    for (int m = 0; m < 4; ++m) {
        const int oc = 16 * m + 4 * g;
        const float4 bb = *(const float4*)(sb + oc);
        #pragma unroll
        for (int c = 0; c < 4; ++c) {
            const int px = p0 + 4 * i + c;
            const int h = px / W56, ww = px - h * W56;
            f16x4 st;
            st[0] = (f16)fmaxf(acc[m][c][0] + bb.x, 0.f);
            st[1] = (f16)fmaxf(acc[m][c][1] + bb.y, 0.f);
            st[2] = (f16)fmaxf(acc[m][c][2] + bb.z, 0.f);
            st[3] = (f16)fmaxf(acc[m][c][3] + bb.w, 0.f);
            *(f16x4*)(Spad + ((size_t)n * SPAD + (h + 1) * PW + ww + 1) * CSQ + oc) = st;
        }
    }
}

// ---------------------------------------------------------------------------
// expand1x1: reads padded S directly.  Wave wv: out-ch 64wv..+63, px p0..+63.
// ---------------------------------------------------------------------------
__global__ __launch_bounds__(256) void fire_expand1p(
    const f16* __restrict__ Spad, const f16* __restrict__ W1,
    const float* __restrict__ b1, float* __restrict__ out)
{
    const int tid  = threadIdx.x;
    const int lane = tid & 63, wv = tid >> 6;
    const int i = lane & 15, g = lane >> 4;
    const int n  = blockIdx.y;
    const int p0 = blockIdx.x * 64;

    const f16* Sn = Spad + (size_t)n * SPAD * CSQ;

    // per-lane padded position for the 4 px fragments
    int q[4];
    #pragma unroll
    for (int c = 0; c < 4; ++c) {
        const int px = p0 + 16 * c + i;
        const int h = px / W56, ww = px - h * W56;
        q[c] = (h + 1) * PW + ww + 1;
    }

    f32x4 acc[4][4] = {};
    #pragma unroll
    for (int kk = 0; kk < 2; ++kk) {
        const int k0 = kk * 32 + g * 8;
        f16x8 b[4];
        #pragma unroll
        for (int c = 0; c < 4; ++c)
            b[c] = *(const f16x8*)(Sn + (size_t)q[c] * CSQ + k0);
        #pragma unroll
        for (int m = 0; m < 4; ++m) {
            f16x8 a = *(const f16x8*)(W1 + (64 * wv + 16 * m + i) * CSQ + k0);
            #pragma unroll
            for (int c = 0; c < 4; ++c)
                acc[m][c] = MFMA(a, b[c], acc[m][c]);
        }
    }

    #pragma unroll
    for (int m = 0; m < 4; ++m) {
        const int oc = 64 * wv + 16 * m + 4 * g;
        const float4 bb = *(const float4*)(b1 + oc);
        #pragma unroll
        for (int c = 0; c < 4; ++c) {
            float* op = out + ((size_t)n * 512 + oc) * HW + p0 + 16 * c + i;
            op[0 * (size_t)HW] = fmaxf(acc[m][c][0] + bb.x, 0.f);
            op[1 * (size_t)HW] = fmaxf(acc[m][c][1] + bb.y, 0.f);
            op[2 * (size_t)HW] = fmaxf(acc[m][c][2] + bb.z, 0.f);
            op[3 * (size_t)HW] = fmaxf(acc[m][c][3] + bb.w, 0.f);
        }
    }
}

// ---------------------------------------------------------------------------
// expand3x3 v4: v2 math verbatim, but B-frags read DIRECTLY from padded S
// (global, L2-hot, no predication) -- no LDS, no barriers, waves independent.
// block = 4 waves, tile = 256 oc x 112 px (2 rows); 9 taps x K=64.
// ---------------------------------------------------------------------------
__global__ __launch_bounds__(256) void fire_expand3v4(
    const f16* __restrict__ Spad, const f16* __restrict__ W3,
    const float* __restrict__ b3, float* __restrict__ out)
{
    const int tid  = threadIdx.x;
    const int lane = tid & 63, wv = tid >> 6;
    const int i = lane & 15, g = lane >> 4;
    const int n  = blockIdx.y;
    const int rb = blockIdx.x;          // output rows 2rb, 2rb+1
    const f16* Sn = Spad + (size_t)n * SPAD * CSQ;

    // per-lane UNPADDED (h*58+w) base for the 7 px fragments; tap (dh,dw)
    // reads padded pos q0 + dh*58 + dw  (padded row = h+dh, col = w+dw).
    int q0[7];
    #pragma unroll
    for (int c = 0; c < 7; ++c) {
        const int pl = 16 * c + i;            // 0..111
        const int r  = (pl >= W56) ? 1 : 0;
        const int h  = 2 * rb + r;
        const int ww = pl - r * W56;
        q0[c] = h * PW + ww;
    }

    f32x4 acc[4][7] = {};
    for (int tap = 0; tap < 9; ++tap) {
        const int dh = tap / 3, dw = tap - dh * 3;
        const int toff = dh * PW + dw;
        const f16* wtap = W3 + (size_t)tap * CE * CSQ;
        #pragma unroll
        for (int kk = 0; kk < 2; ++kk) {
            const int k0 = kk * 32 + g * 8;
            f16x8 b[7];
            #pragma unroll
            for (int c = 0; c < 7; ++c)
                b[c] = *(const f16x8*)(Sn + (size_t)(q0[c] + toff) * CSQ + k0);
            #pragma unroll
            for (int m = 0; m < 4; ++m) {
                f16x8 a = *(const f16x8*)(wtap + (64 * wv + 16 * m + i) * CSQ + k0);
                #pragma unroll
                for (int c = 0; c < 7; ++c)
                    acc[m][c] = MFMA(a, b[c], acc[m][c]);
            }
        }
    }

    // epilogue: out ch = 256 + (64wv+16m+4g+v), pixel = rb*112+16c+i
    #pragma unroll
    for (int m = 0; m < 4; ++m) {
        const int ocl = 64 * wv + 16 * m + 4 * g;
        const float4 bb = *(const float4*)(b3 + ocl);
        #pragma unroll
        for (int c = 0; c < 7; ++c) {
            float* op = out + ((size_t)n * 512 + 256 + ocl) * HW + rb * 112 + 16 * c + i;
            op[0 * (size_t)HW] = fmaxf(acc[m][c][0] + bb.x, 0.f);
            op[1 * (size_t)HW] = fmaxf(acc[m][c][1] + bb.y, 0.f);
            op[2 * (size_t)HW] = fmaxf(acc[m][c][2] + bb.z, 0.f);
            op[3 * (size_t)HW] = fmaxf(acc[m][c][3] + bb.w, 0.f);
        }
    }
}

// ---------------------------------------------------------------------------
extern "C" void kernel_launch(void* const* d_in, const int* in_sizes, int n_in,
                              void* d_out, int out_size, void* d_ws, size_t ws_size,
                              hipStream_t stream)
{
    const float* x  = (const float*)d_in[0];
    const float* sw = (const float*)d_in[1];
    const float* sb = (const float*)d_in[2];
    const float* w1 = (const float*)d_in[3];
    const float* b1 = (const float*)d_in[4];
    const float* w3 = (const float*)d_in[5];
    const float* b3 = (const float*)d_in[6];
    float* out = (float*)d_out;

    // workspace (fp16): Spad [32][3364][64], Wsq [64][512], W1 [256][64],
    // W3 [9][256][64]
    f16* Spad = (f16*)d_ws;
    f16* Wsq  = Spad + (size_t)NIMG * SPAD * CSQ;
    f16* W1b  = Wsq + CSQ * CIN;
    f16* W3b  = W1b + CE * CSQ;

    fire_prep<<<4132, 256, 0, stream>>>(sw, w1, w3, Wsq, W1b, W3b, Spad);
    fire_squeeze2p<<<392, 256, 0, stream>>>(x, sb, Wsq, Spad);
    fire_expand1p<<<dim3(49, 32), 256, 0, stream>>>(Spad, W1b, b1, out);
    fire_expand3v4<<<dim3(28, 32), 256, 0, stream>>>(Spad, W3b, b3, out);
}